// Round 16
// baseline (396.125 us; speedup 1.0000x reference)
//
#include <hip/hip_runtime.h>
#include <hip/hip_fp16.h>
#include <math.h>

// GAT encoder: N=10000, E=160000 (+N self loops), H=8 heads, C=128, D=1024.
// R11: commute restructure (gather 128-dim P once per edge, per-head GEMM after).
// R12: attn+agg fused per wave (kept).
// R15: tail UN-fused back to hgemm (5000 blocks) + proj (1250 blocks): three
// fused-tail variants (R12/13/14) all pinned at 52-59us with every pipe idle --
// 625-block grids of long serial spans are resident-work-starved regardless of
// intra-block shape. Short spans x large grid wins; G round-trip is cheaper.

#define THREADS 256
#define CAP 128

typedef _Float16 f16x8 __attribute__((ext_vector_type(8)));
typedef float f32x4 __attribute__((ext_vector_type(4)));

struct __align__(8) Half4 { __half2 a, b; };

__device__ __forceinline__ float gelu_exact(float x) {
  return 0.5f * x * (1.0f + erff(x * 0.70710678118654752f));
}

// ---------------- CSR build ----------------

__global__ void hist_kernel(const int* __restrict__ ei, int E, int ET, int* __restrict__ counts) {
  int e = blockIdx.x * THREADS + threadIdx.x;
  if (e >= ET) return;
  int d = (e < E) ? ei[E + e] : (e - E);
  atomicAdd(&counts[d], 1);
}

__global__ __launch_bounds__(1024) void scan_kernel(const int* __restrict__ counts,
                                                    int* __restrict__ offsets,
                                                    int* __restrict__ cursor, int n) {
  __shared__ int sums[1024];
  int t = threadIdx.x;
  int per = (n + 1023) >> 10;
  int start = t * per; if (start > n) start = n;
  int end = start + per; if (end > n) end = n;
  int local = 0;
  for (int i = start; i < end; ++i) local += counts[i];
  sums[t] = local;
  __syncthreads();
  for (int off = 1; off < 1024; off <<= 1) {
    int add = (t >= off) ? sums[t - off] : 0;
    __syncthreads();
    sums[t] += add;
    __syncthreads();
  }
  int run = (t == 0) ? 0 : sums[t - 1];
  for (int i = start; i < end; ++i) {
    offsets[i] = run; cursor[i] = run; run += counts[i];
  }
  if (t == 1023) offsets[n] = run;
}

__global__ void scatter_kernel(const int* __restrict__ ei, int E, int ET,
                               int* __restrict__ cursor, int* __restrict__ srcs) {
  int e = blockIdx.x * THREADS + threadIdx.x;
  if (e >= ET) return;
  int s = (e < E) ? ei[e] : (e - E);
  int d = (e < E) ? ei[E + e] : (e - E);
  int pos = atomicAdd(&cursor[d], 1);
  srcs[pos] = s;
}

// ---------------- batched weight transpose + fp16 convert ----------------

__global__ __launch_bounds__(256) void wconv_all_kernel(
    const float* __restrict__ w2, const float* __restrict__ w3,
    const float* __restrict__ rw1, const float* __restrict__ rw2,
    const float* __restrict__ lw,
    __half* __restrict__ wt2, __half* __restrict__ wt3,
    __half* __restrict__ rwt1, __half* __restrict__ rwt2,
    __half* __restrict__ lwt) {
  const float* in; __half* out; int K, Ncol;
  switch (blockIdx.z) {
    case 0: in = w2;  out = wt2;  K = 128;  Ncol = 1024; break;
    case 1: in = w3;  out = wt3;  K = 128;  Ncol = 1024; break;
    case 2: in = rw1; out = rwt1; K = 1024; Ncol = 128;  break;
    case 3: in = rw2; out = rwt2; K = 1024; Ncol = 128;  break;
    default: in = lw; out = lwt;  K = 1024; Ncol = 128;  break;
  }
  int kb = blockIdx.y * 32, cb = blockIdx.x * 32;
  if (kb >= K || cb >= Ncol) return;
  __shared__ float tile[32][33];
  int t = threadIdx.x;
  int tc = t & 31, tr = t >> 5;
#pragma unroll
  for (int r = tr; r < 32; r += 8)
    tile[r][tc] = in[(size_t)(kb + r) * Ncol + cb + tc];
  __syncthreads();
#pragma unroll
  for (int r = tr; r < 32; r += 8)
    out[(size_t)(cb + r) * K + kb + tc] = __float2half_rn(tile[tc][r]);
}

// ---------------- score-vector precompute ----------------

__global__ __launch_bounds__(256) void sconv_kernel(
    const float* __restrict__ w1, const float* __restrict__ as1, const float* __restrict__ ad1,
    const float* __restrict__ w2, const float* __restrict__ as2, const float* __restrict__ ad2,
    const float* __restrict__ w3, const float* __restrict__ as3, const float* __restrict__ ad3,
    float* __restrict__ ws1, float* __restrict__ wd1,
    float* __restrict__ ws2, float* __restrict__ wd2,
    float* __restrict__ ws3, float* __restrict__ wd3) {
  int h = blockIdx.x;
  int t = threadIdx.x;
  int sel = t >> 7;
  int k = t & 127;
  const float* W; const float* av; float* out; int K;
  switch (blockIdx.y) {
    case 0: W = w2; av = sel ? ad2 : as2; out = sel ? wd2 : ws2; K = 128; break;
    case 1: W = w3; av = sel ? ad3 : as3; out = sel ? wd3 : ws3; K = 128; break;
    default: W = w1; av = sel ? ad1 : as1; out = sel ? wd1 : ws1; K = 4; break;
  }
  if (k >= K) return;
  const float* wrow = W + (size_t)k * 1024 + h * 128;
  const float* arow = av + h * 128;
  float s = 0.f;
  for (int c = 0; c < 128; c += 4) {
    float4 wv = *(const float4*)&wrow[c];
    float4 a4 = *(const float4*)&arow[c];
    s += wv.x * a4.x + wv.y * a4.y + wv.z * a4.z + wv.w * a4.w;
  }
  out[h * K + k] = s;
}

// ---------------- layer-1 scores ----------------

__global__ void scoresX_kernel(const float* __restrict__ x,
                               const float* __restrict__ ws1, const float* __restrict__ wd1,
                               float* __restrict__ ssrc, float* __restrict__ sdst, int total) {
  int idx = blockIdx.x * THREADS + threadIdx.x;
  if (idx >= total) return;
  int n = idx >> 3, h = idx & 7;
  float4 xv = *(const float4*)&x[n * 4];
  float4 a = *(const float4*)&ws1[h * 4];
  float4 b = *(const float4*)&wd1[h * 4];
  ssrc[idx] = xv.x * a.x + xv.y * a.y + xv.z * a.z + xv.w * a.w;
  sdst[idx] = xv.x * b.x + xv.y * b.y + xv.z * b.z + xv.w * b.w;
}

// ---------------- layer-2/3 scores ----------------

__global__ __launch_bounds__(256) void scoresP_kernel(const __half* __restrict__ P16,
                                                      const float* __restrict__ ws,
                                                      const float* __restrict__ wd,
                                                      float* __restrict__ ssrc,
                                                      float* __restrict__ sdst) {
  int wave = threadIdx.x >> 6, lane = threadIdx.x & 63;
  int n = blockIdx.x * 4 + wave;
  int head = lane & 7, es = lane >> 3;
  const __half* pp = P16 + (size_t)n * 128 + es * 16;
  f16x8 p0 = *(const f16x8*)pp;
  f16x8 p1 = *(const f16x8*)(pp + 8);
  const float* wsp = ws + head * 128 + es * 16;
  const float* wdp = wd + head * 128 + es * 16;
  float s1 = 0.f, s2 = 0.f;
#pragma unroll
  for (int j = 0; j < 8; ++j) {
    s1 += (float)p0[j] * wsp[j];
    s2 += (float)p0[j] * wdp[j];
  }
#pragma unroll
  for (int j = 0; j < 8; ++j) {
    s1 += (float)p1[j] * wsp[8 + j];
    s2 += (float)p1[j] * wdp[8 + j];
  }
#pragma unroll
  for (int mask = 8; mask <= 32; mask <<= 1) {
    s1 += __shfl_xor(s1, mask);
    s2 += __shfl_xor(s2, mask);
  }
  if (es == 0) { ssrc[n * 8 + head] = s1; sdst[n * 8 + head] = s2; }
}

// ---------------- fused attention + aggregation (P16), wave per node ----------------

__global__ __launch_bounds__(256) void attnagg_p(const __half* __restrict__ P16,
                                                 const int* __restrict__ srcs,
                                                 const int* __restrict__ offsets,
                                                 const float* __restrict__ ssrc,
                                                 const float* __restrict__ sdst,
                                                 __half* __restrict__ Y16, int N) {
  __shared__ float lal[4][CAP][8];
  __shared__ int ls[4][CAP];
  __shared__ float szinv[4][8];
  int w = threadIdx.x >> 6, lane = threadIdx.x & 63;
  int n = blockIdx.x * 4 + w;
  int start = offsets[n], deg = offsets[n + 1] - start;
  int head = lane & 7, es = lane >> 3;
  float sd = sdst[n * 8 + head];
  int c2 = lane * 2;
  float accx[8] = {}, accy[8] = {};
  float s = 0.f;
  for (int cc = 0; cc < deg; cc += CAP) {
    int cm = min(CAP, deg - cc);
    for (int i = es; i < cm; i += 8) {
      int sp = srcs[start + cc + i];
      float v = ssrc[sp * 8 + head] + sd;
      v = (v > 0.f) ? v : 0.2f * v;
      float e = __expf(v);
      lal[w][i][head] = e;
      if (head == 0) ls[w][i] = sp;
      s += e;
    }
    int i = 0;
    for (; i + 1 < cm; i += 2) {
      int sp0 = ls[w][i], sp1 = ls[w][i + 1];
      float4 a00 = *(float4*)&lal[w][i][0];
      float4 a01 = *(float4*)&lal[w][i][4];
      float4 a10 = *(float4*)&lal[w][i + 1][0];
      float4 a11 = *(float4*)&lal[w][i + 1][4];
      float2 p0 = __half22float2(*(const __half2*)&P16[(size_t)sp0 * 128 + c2]);
      float2 p1 = __half22float2(*(const __half2*)&P16[(size_t)sp1 * 128 + c2]);
      float a0[8] = {a00.x, a00.y, a00.z, a00.w, a01.x, a01.y, a01.z, a01.w};
      float a1[8] = {a10.x, a10.y, a10.z, a10.w, a11.x, a11.y, a11.z, a11.w};
#pragma unroll
      for (int h = 0; h < 8; ++h) {
        accx[h] += a0[h] * p0.x; accy[h] += a0[h] * p0.y;
        accx[h] += a1[h] * p1.x; accy[h] += a1[h] * p1.y;
      }
    }
    if (i < cm) {
      int sp0 = ls[w][i];
      float4 a00 = *(float4*)&lal[w][i][0];
      float4 a01 = *(float4*)&lal[w][i][4];
      float2 p0 = __half22float2(*(const __half2*)&P16[(size_t)sp0 * 128 + c2]);
      float a0[8] = {a00.x, a00.y, a00.z, a00.w, a01.x, a01.y, a01.z, a01.w};
#pragma unroll
      for (int h = 0; h < 8; ++h) {
        accx[h] += a0[h] * p0.x; accy[h] += a0[h] * p0.y;
      }
    }
  }
#pragma unroll
  for (int mask = 8; mask <= 32; mask <<= 1)
    s += __shfl_xor(s, mask);
  if (es == 0) szinv[w][head] = 1.f / s;
#pragma unroll
  for (int h = 0; h < 8; ++h) {
    float zi = szinv[w][h];
    *(__half2*)&Y16[((size_t)h * N + n) * 128 + c2] =
        __floats2half2_rn(accx[h] * zi, accy[h] * zi);
  }
}

// ---------------- fused attention + aggregation (layer 1, raw x) ----------------

__global__ __launch_bounds__(256) void attnagg_x(const float* __restrict__ x,
                                                 const int* __restrict__ srcs,
                                                 const int* __restrict__ offsets,
                                                 const float* __restrict__ ssrc,
                                                 const float* __restrict__ sdst,
                                                 float* __restrict__ Y1, int N) {
  __shared__ float lal[4][CAP][8];
  __shared__ int ls[4][CAP];
  __shared__ float szinv[4][8];
  int w = threadIdx.x >> 6, lane = threadIdx.x & 63;
  int n = blockIdx.x * 4 + w;
  int start = offsets[n], deg = offsets[n + 1] - start;
  int head = lane & 7, es = lane >> 3;
  float sd = sdst[n * 8 + head];
  int eo = lane >> 5, hb = (lane >> 2) & 7, ch = lane & 3;
  float acc = 0.f;
  float s = 0.f;
  for (int cc = 0; cc < deg; cc += CAP) {
    int cm = min(CAP, deg - cc);
    for (int i = es; i < cm; i += 8) {
      int sp = srcs[start + cc + i];
      float v = ssrc[sp * 8 + head] + sd;
      v = (v > 0.f) ? v : 0.2f * v;
      float e = __expf(v);
      lal[w][i][head] = e;
      if (head == 0) ls[w][i] = sp;
      s += e;
    }
    for (int i = eo; i < cm; i += 2) {
      int sp = ls[w][i];
      float a = lal[w][i][hb];
      acc += a * x[sp * 4 + ch];
    }
  }
#pragma unroll
  for (int mask = 8; mask <= 32; mask <<= 1)
    s += __shfl_xor(s, mask);
  if (es == 0) szinv[w][head] = 1.f / s;
  acc += __shfl_xor(acc, 32);
  if (lane < 32) {
    float zi = szinv[w][hb];
    Y1[((size_t)hb * N + n) * 4 + ch] = acc * zi;
  }
}

// ---------------- layer-1 feature transform of aggregated x: G = gelu(Y1@w1 + b) ----------------

__global__ void hgemm1_kernel(const float* __restrict__ Y1, const float* __restrict__ w,
                              const float* __restrict__ bias, __half* __restrict__ G,
                              int N, int total) {
  int idx = blockIdx.x * THREADS + threadIdx.x;
  if (idx >= total) return;   // total = N*256
  int n = idx >> 8, c0 = (idx & 255) * 4;
  int h = c0 >> 7;
  float4 yv = *(const float4*)&Y1[((size_t)h * N + n) * 4];
  float4 wa = *(const float4*)&w[c0];
  float4 wb = *(const float4*)&w[1024 + c0];
  float4 wc = *(const float4*)&w[2048 + c0];
  float4 wd = *(const float4*)&w[3072 + c0];
  float4 b4 = *(const float4*)&bias[c0];
  float o0 = gelu_exact(yv.x * wa.x + yv.y * wb.x + yv.z * wc.x + yv.w * wd.x + b4.x);
  float o1 = gelu_exact(yv.x * wa.y + yv.y * wb.y + yv.z * wc.y + yv.w * wd.y + b4.y);
  float o2 = gelu_exact(yv.x * wa.z + yv.y * wb.z + yv.z * wc.z + yv.w * wd.z + b4.z);
  float o3 = gelu_exact(yv.x * wa.w + yv.y * wb.w + yv.z * wc.w + yv.w * wd.w + b4.w);
  Half4 p;
  p.a = __floats2half2_rn(o0, o1);
  p.b = __floats2half2_rn(o2, o3);
  *(Half4*)&G[(size_t)n * 1024 + c0] = p;
}

// ---------------- per-head MFMA: G[:, hblk] = gelu(Y16[h] @ W[:, hblk] + b) ----------------
// Block = 16 rows x one head's 128 cols; Wt[col][k] (K=128). LDS-staged coalesced store.

__global__ __launch_bounds__(256) void hgemm_kernel(const __half* __restrict__ Y16,
                                                    const __half* __restrict__ Wt,
                                                    const float* __restrict__ bias,
                                                    __half* __restrict__ G, int N) {
  __shared__ __half Gt[16][136];
  int h = blockIdx.x;
  int r0 = blockIdx.y * 16;
  int wave = threadIdx.x >> 6, lane = threadIdx.x & 63;
  int m = lane & 15, quad = lane >> 4;
  const __half* py = Y16 + ((size_t)h * N + r0 + m) * 128 + quad * 8;
  f16x8 bfrag[4];
#pragma unroll
  for (int kk = 0; kk < 4; ++kk)
    bfrag[kk] = *(const f16x8*)(py + kk * 32);
#pragma unroll
  for (int tile = 0; tile < 2; ++tile) {
    int cl = wave * 32 + tile * 16;
    int gc = h * 128 + cl;
    const __half* pa = Wt + (size_t)(gc + m) * 128 + quad * 8;
    f32x4 acc = {0.f, 0.f, 0.f, 0.f};
#pragma unroll
    for (int kk = 0; kk < 4; ++kk) {
      f16x8 a = *(const f16x8*)(pa + kk * 32);
      acc = __builtin_amdgcn_mfma_f32_16x16x32_f16(a, bfrag[kk], acc, 0, 0, 0);
    }
    float4 b4 = *(const float4*)&bias[gc + quad * 4];
    float o0 = gelu_exact(acc[0] + b4.x);
    float o1 = gelu_exact(acc[1] + b4.y);
    float o2 = gelu_exact(acc[2] + b4.z);
    float o3 = gelu_exact(acc[3] + b4.w);
    Half4 p;
    p.a = __floats2half2_rn(o0, o1);
    p.b = __floats2half2_rn(o2, o3);
    *(Half4*)&Gt[m][cl + quad * 4] = p;
  }
  __syncthreads();
  int t = threadIdx.x;
  int row = t >> 4, c8 = (t & 15) * 8;
  *(float4*)&G[(size_t)(r0 + row) * 1024 + h * 128 + c8] = *(float4*)&Gt[row][c8];
}

// ---------------- MFMA proj: G[N,1024] @ W[1024,128] + bias -> C[N,128] ----------------

template <typename OutT>
__global__ __launch_bounds__(256) void proj_mfma(const __half* __restrict__ G,
                                                 const __half* __restrict__ Wt,
                                                 const float* __restrict__ bias,
                                                 OutT* __restrict__ C) {
  int wave = threadIdx.x >> 6, lane = threadIdx.x & 63;
  int r0 = blockIdx.y * 16;
  int c0 = blockIdx.x * 64 + wave * 16;
  int m = lane & 15, quad = lane >> 4;
  const __half* pa = Wt + (size_t)(c0 + m) * 1024 + quad * 8;
  const __half* pb = G + (size_t)(r0 + m) * 1024 + quad * 8;
  f32x4 acc = {0.f, 0.f, 0.f, 0.f};
#pragma unroll 8
  for (int k = 0; k < 1024; k += 32) {
    f16x8 a = *(const f16x8*)(pa + k);
    f16x8 b = *(const f16x8*)(pb + k);
    acc = __builtin_amdgcn_mfma_f32_16x16x32_f16(a, b, acc, 0, 0, 0);
  }
  float4 b4 = *(const float4*)&bias[c0 + quad * 4];
  float v0 = acc[0] + b4.x, v1 = acc[1] + b4.y, v2 = acc[2] + b4.z, v3 = acc[3] + b4.w;
  if constexpr (__is_same(OutT, __half)) {
    Half4 p;
    p.a = __floats2half2_rn(v0, v1);
    p.b = __floats2half2_rn(v2, v3);
    *(Half4*)&C[(size_t)(r0 + m) * 128 + c0 + quad * 4] = p;
  } else {
    *(float4*)&C[(size_t)(r0 + m) * 128 + c0 + quad * 4] = make_float4(v0, v1, v2, v3);
  }
}

// ---------------- orchestration ----------------

extern "C" void kernel_launch(void* const* d_in, const int* in_sizes, int n_in,
                              void* d_out, int out_size, void* d_ws, size_t ws_size,
                              hipStream_t stream) {
  const float* x   = (const float*)d_in[0];
  const int*   ei  = (const int*)d_in[1];
  const float* w1  = (const float*)d_in[2];
  const float* as1 = (const float*)d_in[3];
  const float* ad1 = (const float*)d_in[4];
  const float* b1  = (const float*)d_in[5];
  const float* w2  = (const float*)d_in[6];
  const float* as2 = (const float*)d_in[7];
  const float* ad2 = (const float*)d_in[8];
  const float* b2  = (const float*)d_in[9];
  const float* w3  = (const float*)d_in[10];
  const float* as3 = (const float*)d_in[11];
  const float* ad3 = (const float*)d_in[12];
  const float* b3  = (const float*)d_in[13];
  const float* rw1 = (const float*)d_in[14];
  const float* rb1 = (const float*)d_in[15];
  const float* rw2 = (const float*)d_in[16];
  const float* rb2 = (const float*)d_in[17];
  const float* lw  = (const float*)d_in[18];
  const float* lb  = (const float*)d_in[19];

  int N = in_sizes[0] / 4;
  int E = in_sizes[1] / 2;
  int ET = E + N;
  (void)ws_size;

  char* wsb = (char*)d_ws;
  size_t off = 0;
  auto alloc = [&](size_t bytes) -> void* {
    void* p = wsb + off;
    off += (bytes + 255) & ~(size_t)255;
    return p;
  };
  __half* G    = (__half*)alloc((size_t)N * 1024 * 2);
  __half* P16  = (__half*)alloc((size_t)N * 128 * 2);
  __half* Y16  = (__half*)alloc((size_t)8 * N * 128 * 2);
  float*  Y1   = (float*)alloc((size_t)8 * N * 4 * 4);
  __half* wt2  = (__half*)alloc((size_t)1024 * 128 * 2);
  __half* wt3  = (__half*)alloc((size_t)1024 * 128 * 2);
  __half* rwt1 = (__half*)alloc((size_t)128 * 1024 * 2);
  __half* rwt2 = (__half*)alloc((size_t)128 * 1024 * 2);
  __half* lwt  = (__half*)alloc((size_t)128 * 1024 * 2);
  float* ws1 = (float*)alloc(8 * 4 * 4);
  float* wd1 = (float*)alloc(8 * 4 * 4);
  float* ws2 = (float*)alloc(8 * 128 * 4);
  float* wd2 = (float*)alloc(8 * 128 * 4);
  float* ws3 = (float*)alloc(8 * 128 * 4);
  float* wd3 = (float*)alloc(8 * 128 * 4);
  float* ssrc   = (float*)alloc((size_t)N * 8 * 4);
  float* sdst   = (float*)alloc((size_t)N * 8 * 4);
  int* counts  = (int*)alloc((size_t)N * 4);
  int* offsets = (int*)alloc((size_t)(N + 1) * 4);
  int* cursor  = (int*)alloc((size_t)N * 4);
  int* srcs    = (int*)alloc((size_t)ET * 4);

  dim3 blk(THREADS);

  hipMemsetAsync(counts, 0, (size_t)N * 4, stream);
  hist_kernel<<<dim3((ET + THREADS - 1) / THREADS), blk, 0, stream>>>(ei, E, ET, counts);
  wconv_all_kernel<<<dim3(32, 32, 5), blk, 0, stream>>>(w2, w3, rw1, rw2, lw,
                                                        wt2, wt3, rwt1, rwt2, lwt);
  sconv_kernel<<<dim3(8, 3), blk, 0, stream>>>(w1, as1, ad1, w2, as2, ad2, w3, as3, ad3,
                                               ws1, wd1, ws2, wd2, ws3, wd3);
  scan_kernel<<<dim3(1), dim3(1024), 0, stream>>>(counts, offsets, cursor, N);
  scatter_kernel<<<dim3((ET + THREADS - 1) / THREADS), blk, 0, stream>>>(ei, E, ET, cursor, srcs);

  dim3 gNode4(N / 4);
  dim3 gHg(8, N / 16);
  dim3 gProj(2, N / 16);

  // ---- layer 1 ----
  scoresX_kernel<<<dim3((N * 8 + THREADS - 1) / THREADS), blk, 0, stream>>>(
      x, ws1, wd1, ssrc, sdst, N * 8);
  attnagg_x<<<gNode4, blk, 0, stream>>>(x, srcs, offsets, ssrc, sdst, Y1, N);
  hgemm1_kernel<<<dim3(N), blk, 0, stream>>>(Y1, w1, b1, G, N, N * 256);
  proj_mfma<__half><<<gProj, blk, 0, stream>>>(G, rwt1, rb1, P16);

  // ---- layer 2 ----
  scoresP_kernel<<<gNode4, blk, 0, stream>>>(P16, ws2, wd2, ssrc, sdst);
  attnagg_p<<<gNode4, blk, 0, stream>>>(P16, srcs, offsets, ssrc, sdst, Y16, N);
  hgemm_kernel<<<gHg, blk, 0, stream>>>(Y16, wt2, b2, G, N);
  proj_mfma<__half><<<gProj, blk, 0, stream>>>(G, rwt2, rb2, P16);

  // ---- layer 3 ----
  scoresP_kernel<<<gNode4, blk, 0, stream>>>(P16, ws3, wd3, ssrc, sdst);
  attnagg_p<<<gNode4, blk, 0, stream>>>(P16, srcs, offsets, ssrc, sdst, Y16, N);
  hgemm_kernel<<<gHg, blk, 0, stream>>>(Y16, wt3, b3, G, N);
  proj_mfma<float><<<gProj, blk, 0, stream>>>(G, lwt, lb, (float*)d_out);
}

// Round 17
// 309.579 us; speedup vs baseline: 1.2796x; 1.2796x over previous
//
#include <hip/hip_runtime.h>
#include <hip/hip_fp16.h>
#include <math.h>

// GAT encoder: N=10000, E=160000 (+N self loops), H=8 heads, C=128, D=1024.
// R11: commute restructure (gather 128-dim P once per edge, per-head GEMM after).
// R12: attn+agg fused per wave. R13: fused tail, 512 thr. R15: un-fuse regressed
// (G round-trip costs more). R16: tail register-blocks 2 row-tiles per wave
// (32-row blocks) -- each weight fragment loaded once serves 2 MFMAs, halving
// the 320 MB/dispatch L2 weight re-read that pinned R12-R14 tails at ~52us.

#define THREADS 256
#define CAP 128

typedef _Float16 f16x8 __attribute__((ext_vector_type(8)));
typedef float f32x4 __attribute__((ext_vector_type(4)));

struct __align__(8) Half4 { __half2 a, b; };

__device__ __forceinline__ float gelu_exact(float x) {
  return 0.5f * x * (1.0f + erff(x * 0.70710678118654752f));
}

// ---------------- CSR build ----------------

__global__ void hist_kernel(const int* __restrict__ ei, int E, int ET, int* __restrict__ counts) {
  int e = blockIdx.x * THREADS + threadIdx.x;
  if (e >= ET) return;
  int d = (e < E) ? ei[E + e] : (e - E);
  atomicAdd(&counts[d], 1);
}

__global__ __launch_bounds__(1024) void scan_kernel(const int* __restrict__ counts,
                                                    int* __restrict__ offsets,
                                                    int* __restrict__ cursor, int n) {
  __shared__ int sums[1024];
  int t = threadIdx.x;
  int per = (n + 1023) >> 10;
  int start = t * per; if (start > n) start = n;
  int end = start + per; if (end > n) end = n;
  int local = 0;
  for (int i = start; i < end; ++i) local += counts[i];
  sums[t] = local;
  __syncthreads();
  for (int off = 1; off < 1024; off <<= 1) {
    int add = (t >= off) ? sums[t - off] : 0;
    __syncthreads();
    sums[t] += add;
    __syncthreads();
  }
  int run = (t == 0) ? 0 : sums[t - 1];
  for (int i = start; i < end; ++i) {
    offsets[i] = run; cursor[i] = run; run += counts[i];
  }
  if (t == 1023) offsets[n] = run;
}

__global__ void scatter_kernel(const int* __restrict__ ei, int E, int ET,
                               int* __restrict__ cursor, int* __restrict__ srcs) {
  int e = blockIdx.x * THREADS + threadIdx.x;
  if (e >= ET) return;
  int s = (e < E) ? ei[e] : (e - E);
  int d = (e < E) ? ei[E + e] : (e - E);
  int pos = atomicAdd(&cursor[d], 1);
  srcs[pos] = s;
}

// ---------------- batched weight transpose + fp16 convert ----------------

__global__ __launch_bounds__(256) void wconv_all_kernel(
    const float* __restrict__ w2, const float* __restrict__ w3,
    const float* __restrict__ rw1, const float* __restrict__ rw2,
    const float* __restrict__ lw,
    __half* __restrict__ wt2, __half* __restrict__ wt3,
    __half* __restrict__ rwt1, __half* __restrict__ rwt2,
    __half* __restrict__ lwt) {
  const float* in; __half* out; int K, Ncol;
  switch (blockIdx.z) {
    case 0: in = w2;  out = wt2;  K = 128;  Ncol = 1024; break;
    case 1: in = w3;  out = wt3;  K = 128;  Ncol = 1024; break;
    case 2: in = rw1; out = rwt1; K = 1024; Ncol = 128;  break;
    case 3: in = rw2; out = rwt2; K = 1024; Ncol = 128;  break;
    default: in = lw; out = lwt;  K = 1024; Ncol = 128;  break;
  }
  int kb = blockIdx.y * 32, cb = blockIdx.x * 32;
  if (kb >= K || cb >= Ncol) return;
  __shared__ float tile[32][33];
  int t = threadIdx.x;
  int tc = t & 31, tr = t >> 5;
#pragma unroll
  for (int r = tr; r < 32; r += 8)
    tile[r][tc] = in[(size_t)(kb + r) * Ncol + cb + tc];
  __syncthreads();
#pragma unroll
  for (int r = tr; r < 32; r += 8)
    out[(size_t)(cb + r) * K + kb + tc] = __float2half_rn(tile[tc][r]);
}

// ---------------- score-vector precompute ----------------

__global__ __launch_bounds__(256) void sconv_kernel(
    const float* __restrict__ w1, const float* __restrict__ as1, const float* __restrict__ ad1,
    const float* __restrict__ w2, const float* __restrict__ as2, const float* __restrict__ ad2,
    const float* __restrict__ w3, const float* __restrict__ as3, const float* __restrict__ ad3,
    float* __restrict__ ws1, float* __restrict__ wd1,
    float* __restrict__ ws2, float* __restrict__ wd2,
    float* __restrict__ ws3, float* __restrict__ wd3) {
  int h = blockIdx.x;
  int t = threadIdx.x;
  int sel = t >> 7;
  int k = t & 127;
  const float* W; const float* av; float* out; int K;
  switch (blockIdx.y) {
    case 0: W = w2; av = sel ? ad2 : as2; out = sel ? wd2 : ws2; K = 128; break;
    case 1: W = w3; av = sel ? ad3 : as3; out = sel ? wd3 : ws3; K = 128; break;
    default: W = w1; av = sel ? ad1 : as1; out = sel ? wd1 : ws1; K = 4; break;
  }
  if (k >= K) return;
  const float* wrow = W + (size_t)k * 1024 + h * 128;
  const float* arow = av + h * 128;
  float s = 0.f;
  for (int c = 0; c < 128; c += 4) {
    float4 wv = *(const float4*)&wrow[c];
    float4 a4 = *(const float4*)&arow[c];
    s += wv.x * a4.x + wv.y * a4.y + wv.z * a4.z + wv.w * a4.w;
  }
  out[h * K + k] = s;
}

// ---------------- layer-1 scores ----------------

__global__ void scoresX_kernel(const float* __restrict__ x,
                               const float* __restrict__ ws1, const float* __restrict__ wd1,
                               float* __restrict__ ssrc, float* __restrict__ sdst, int total) {
  int idx = blockIdx.x * THREADS + threadIdx.x;
  if (idx >= total) return;
  int n = idx >> 3, h = idx & 7;
  float4 xv = *(const float4*)&x[n * 4];
  float4 a = *(const float4*)&ws1[h * 4];
  float4 b = *(const float4*)&wd1[h * 4];
  ssrc[idx] = xv.x * a.x + xv.y * a.y + xv.z * a.z + xv.w * a.w;
  sdst[idx] = xv.x * b.x + xv.y * b.y + xv.z * b.z + xv.w * b.w;
}

// ---------------- layer-2/3 scores ----------------

__global__ __launch_bounds__(256) void scoresP_kernel(const __half* __restrict__ P16,
                                                      const float* __restrict__ ws,
                                                      const float* __restrict__ wd,
                                                      float* __restrict__ ssrc,
                                                      float* __restrict__ sdst) {
  int wave = threadIdx.x >> 6, lane = threadIdx.x & 63;
  int n = blockIdx.x * 4 + wave;
  int head = lane & 7, es = lane >> 3;
  const __half* pp = P16 + (size_t)n * 128 + es * 16;
  f16x8 p0 = *(const f16x8*)pp;
  f16x8 p1 = *(const f16x8*)(pp + 8);
  const float* wsp = ws + head * 128 + es * 16;
  const float* wdp = wd + head * 128 + es * 16;
  float s1 = 0.f, s2 = 0.f;
#pragma unroll
  for (int j = 0; j < 8; ++j) {
    s1 += (float)p0[j] * wsp[j];
    s2 += (float)p0[j] * wdp[j];
  }
#pragma unroll
  for (int j = 0; j < 8; ++j) {
    s1 += (float)p1[j] * wsp[8 + j];
    s2 += (float)p1[j] * wdp[8 + j];
  }
#pragma unroll
  for (int mask = 8; mask <= 32; mask <<= 1) {
    s1 += __shfl_xor(s1, mask);
    s2 += __shfl_xor(s2, mask);
  }
  if (es == 0) { ssrc[n * 8 + head] = s1; sdst[n * 8 + head] = s2; }
}

// ---------------- fused attention + aggregation (P16), wave per node ----------------

__global__ __launch_bounds__(256) void attnagg_p(const __half* __restrict__ P16,
                                                 const int* __restrict__ srcs,
                                                 const int* __restrict__ offsets,
                                                 const float* __restrict__ ssrc,
                                                 const float* __restrict__ sdst,
                                                 __half* __restrict__ Y16, int NP) {
  __shared__ float lal[4][CAP][8];
  __shared__ int ls[4][CAP];
  __shared__ float szinv[4][8];
  int w = threadIdx.x >> 6, lane = threadIdx.x & 63;
  int n = blockIdx.x * 4 + w;
  int start = offsets[n], deg = offsets[n + 1] - start;
  int head = lane & 7, es = lane >> 3;
  float sd = sdst[n * 8 + head];
  int c2 = lane * 2;
  float accx[8] = {}, accy[8] = {};
  float s = 0.f;
  for (int cc = 0; cc < deg; cc += CAP) {
    int cm = min(CAP, deg - cc);
    for (int i = es; i < cm; i += 8) {
      int sp = srcs[start + cc + i];
      float v = ssrc[sp * 8 + head] + sd;
      v = (v > 0.f) ? v : 0.2f * v;
      float e = __expf(v);
      lal[w][i][head] = e;
      if (head == 0) ls[w][i] = sp;
      s += e;
    }
    int i = 0;
    for (; i + 1 < cm; i += 2) {
      int sp0 = ls[w][i], sp1 = ls[w][i + 1];
      float4 a00 = *(float4*)&lal[w][i][0];
      float4 a01 = *(float4*)&lal[w][i][4];
      float4 a10 = *(float4*)&lal[w][i + 1][0];
      float4 a11 = *(float4*)&lal[w][i + 1][4];
      float2 p0 = __half22float2(*(const __half2*)&P16[(size_t)sp0 * 128 + c2]);
      float2 p1 = __half22float2(*(const __half2*)&P16[(size_t)sp1 * 128 + c2]);
      float a0[8] = {a00.x, a00.y, a00.z, a00.w, a01.x, a01.y, a01.z, a01.w};
      float a1[8] = {a10.x, a10.y, a10.z, a10.w, a11.x, a11.y, a11.z, a11.w};
#pragma unroll
      for (int h = 0; h < 8; ++h) {
        accx[h] += a0[h] * p0.x; accy[h] += a0[h] * p0.y;
        accx[h] += a1[h] * p1.x; accy[h] += a1[h] * p1.y;
      }
    }
    if (i < cm) {
      int sp0 = ls[w][i];
      float4 a00 = *(float4*)&lal[w][i][0];
      float4 a01 = *(float4*)&lal[w][i][4];
      float2 p0 = __half22float2(*(const __half2*)&P16[(size_t)sp0 * 128 + c2]);
      float a0[8] = {a00.x, a00.y, a00.z, a00.w, a01.x, a01.y, a01.z, a01.w};
#pragma unroll
      for (int h = 0; h < 8; ++h) {
        accx[h] += a0[h] * p0.x; accy[h] += a0[h] * p0.y;
      }
    }
  }
#pragma unroll
  for (int mask = 8; mask <= 32; mask <<= 1)
    s += __shfl_xor(s, mask);
  if (es == 0) szinv[w][head] = 1.f / s;
#pragma unroll
  for (int h = 0; h < 8; ++h) {
    float zi = szinv[w][h];
    *(__half2*)&Y16[((size_t)h * NP + n) * 128 + c2] =
        __floats2half2_rn(accx[h] * zi, accy[h] * zi);
  }
}

// ---------------- fused attention + aggregation (layer 1, raw x) ----------------

__global__ __launch_bounds__(256) void attnagg_x(const float* __restrict__ x,
                                                 const int* __restrict__ srcs,
                                                 const int* __restrict__ offsets,
                                                 const float* __restrict__ ssrc,
                                                 const float* __restrict__ sdst,
                                                 float* __restrict__ Y1, int NP) {
  __shared__ float lal[4][CAP][8];
  __shared__ int ls[4][CAP];
  __shared__ float szinv[4][8];
  int w = threadIdx.x >> 6, lane = threadIdx.x & 63;
  int n = blockIdx.x * 4 + w;
  int start = offsets[n], deg = offsets[n + 1] - start;
  int head = lane & 7, es = lane >> 3;
  float sd = sdst[n * 8 + head];
  int eo = lane >> 5, hb = (lane >> 2) & 7, ch = lane & 3;
  float acc = 0.f;
  float s = 0.f;
  for (int cc = 0; cc < deg; cc += CAP) {
    int cm = min(CAP, deg - cc);
    for (int i = es; i < cm; i += 8) {
      int sp = srcs[start + cc + i];
      float v = ssrc[sp * 8 + head] + sd;
      v = (v > 0.f) ? v : 0.2f * v;
      float e = __expf(v);
      lal[w][i][head] = e;
      if (head == 0) ls[w][i] = sp;
      s += e;
    }
    for (int i = eo; i < cm; i += 2) {
      int sp = ls[w][i];
      float a = lal[w][i][hb];
      acc += a * x[sp * 4 + ch];
    }
  }
#pragma unroll
  for (int mask = 8; mask <= 32; mask <<= 1)
    s += __shfl_xor(s, mask);
  if (es == 0) szinv[w][head] = 1.f / s;
  acc += __shfl_xor(acc, 32);
  if (lane < 32) {
    float zi = szinv[w][hb];
    Y1[((size_t)hb * NP + n) * 4 + ch] = acc * zi;
  }
}

// ---------------- fused tail (layers 2/3), 512 threads, 32 rows, row-blocked ----------------
// Stage 1: wave w = head w; each WtA fragment loaded once serves 2 row-tiles
// (2 MFMAs). Stage 2: wave w = col-tile w; each WtP fragment serves 2 LDS rows.

template <typename OutT>
__global__ __launch_bounds__(512) void tail_mfma(const __half* __restrict__ Y16,
                                                 const __half* __restrict__ WtA,
                                                 const float* __restrict__ biasA,
                                                 const __half* __restrict__ WtP,
                                                 const float* __restrict__ biasP,
                                                 OutT* __restrict__ out, int N, int NP) {
  __shared__ __half Gt[32][1032];
  int w = threadIdx.x >> 6, lane = threadIdx.x & 63;
  int r0 = blockIdx.x * 32;
  int m = lane & 15, quad = lane >> 4;
  // stage 1
  {
    int h = w;
    const __half* py0 = Y16 + ((size_t)h * NP + r0 + m) * 128 + quad * 8;
    const __half* py1 = py0 + (size_t)16 * 128;
    f16x8 bf0[4], bf1[4];
#pragma unroll
    for (int kk = 0; kk < 4; ++kk) {
      bf0[kk] = *(const f16x8*)(py0 + kk * 32);
      bf1[kk] = *(const f16x8*)(py1 + kk * 32);
    }
#pragma unroll
    for (int tile = 0; tile < 8; ++tile) {
      int gc = h * 128 + tile * 16;
      const __half* pa = WtA + (size_t)(gc + m) * 128 + quad * 8;
      f16x8 a[4];
#pragma unroll
      for (int kk = 0; kk < 4; ++kk) a[kk] = *(const f16x8*)(pa + kk * 32);
      f32x4 acc0 = {0.f, 0.f, 0.f, 0.f}, acc1 = {0.f, 0.f, 0.f, 0.f};
#pragma unroll
      for (int kk = 0; kk < 4; ++kk) {
        acc0 = __builtin_amdgcn_mfma_f32_16x16x32_f16(a[kk], bf0[kk], acc0, 0, 0, 0);
        acc1 = __builtin_amdgcn_mfma_f32_16x16x32_f16(a[kk], bf1[kk], acc1, 0, 0, 0);
      }
      float4 b4 = *(const float4*)&biasA[gc + quad * 4];
      Half4 p0, p1;
      p0.a = __floats2half2_rn(gelu_exact(acc0[0] + b4.x), gelu_exact(acc0[1] + b4.y));
      p0.b = __floats2half2_rn(gelu_exact(acc0[2] + b4.z), gelu_exact(acc0[3] + b4.w));
      p1.a = __floats2half2_rn(gelu_exact(acc1[0] + b4.x), gelu_exact(acc1[1] + b4.y));
      p1.b = __floats2half2_rn(gelu_exact(acc1[2] + b4.z), gelu_exact(acc1[3] + b4.w));
      *(Half4*)&Gt[m][gc + quad * 4] = p0;
      *(Half4*)&Gt[16 + m][gc + quad * 4] = p1;
    }
  }
  __syncthreads();
  // stage 2
  {
    int c0 = w * 16;
    const __half* pa = WtP + (size_t)(c0 + m) * 1024 + quad * 8;
    f32x4 acc0 = {0.f, 0.f, 0.f, 0.f}, acc1 = {0.f, 0.f, 0.f, 0.f};
#pragma unroll 8
    for (int k = 0; k < 1024; k += 32) {
      f16x8 a = *(const f16x8*)(pa + k);
      f16x8 b0 = *(const f16x8*)&Gt[m][quad * 8 + k];
      f16x8 b1 = *(const f16x8*)&Gt[16 + m][quad * 8 + k];
      acc0 = __builtin_amdgcn_mfma_f32_16x16x32_f16(a, b0, acc0, 0, 0, 0);
      acc1 = __builtin_amdgcn_mfma_f32_16x16x32_f16(a, b1, acc1, 0, 0, 0);
    }
    float4 b4 = *(const float4*)&biasP[c0 + quad * 4];
    int row0 = r0 + m, row1 = r0 + 16 + m;
    if constexpr (__is_same(OutT, __half)) {
      Half4 p;
      if (row0 < N) {
        p.a = __floats2half2_rn(acc0[0] + b4.x, acc0[1] + b4.y);
        p.b = __floats2half2_rn(acc0[2] + b4.z, acc0[3] + b4.w);
        *(Half4*)&out[(size_t)row0 * 128 + c0 + quad * 4] = p;
      }
      if (row1 < N) {
        p.a = __floats2half2_rn(acc1[0] + b4.x, acc1[1] + b4.y);
        p.b = __floats2half2_rn(acc1[2] + b4.z, acc1[3] + b4.w);
        *(Half4*)&out[(size_t)row1 * 128 + c0 + quad * 4] = p;
      }
    } else {
      if (row0 < N)
        *(float4*)&out[(size_t)row0 * 128 + c0 + quad * 4] =
            make_float4(acc0[0] + b4.x, acc0[1] + b4.y, acc0[2] + b4.z, acc0[3] + b4.w);
      if (row1 < N)
        *(float4*)&out[(size_t)row1 * 128 + c0 + quad * 4] =
            make_float4(acc1[0] + b4.x, acc1[1] + b4.y, acc1[2] + b4.z, acc1[3] + b4.w);
    }
  }
}

// ---------------- fused tail (layer 1), 512 threads, 32 rows ----------------

template <typename OutT>
__global__ __launch_bounds__(512) void tail1_kernel(const float* __restrict__ Y1,
                                                    const float* __restrict__ w,
                                                    const float* __restrict__ biasA,
                                                    const __half* __restrict__ WtP,
                                                    const float* __restrict__ biasP,
                                                    OutT* __restrict__ out, int N, int NP) {
  __shared__ __half Gt[32][1032];
  int t = threadIdx.x;
  int r0 = blockIdx.x * 32;
  {
    int c0 = (t & 255) * 4;
    int h = c0 >> 7;
    float4 wa = *(const float4*)&w[c0];
    float4 wb = *(const float4*)&w[1024 + c0];
    float4 wc = *(const float4*)&w[2048 + c0];
    float4 wd = *(const float4*)&w[3072 + c0];
    float4 b4 = *(const float4*)&biasA[c0];
#pragma unroll 4
    for (int r = t >> 8; r < 32; r += 2) {
      float4 yv = *(const float4*)&Y1[((size_t)h * NP + r0 + r) * 4];
      float o0 = gelu_exact(yv.x * wa.x + yv.y * wb.x + yv.z * wc.x + yv.w * wd.x + b4.x);
      float o1 = gelu_exact(yv.x * wa.y + yv.y * wb.y + yv.z * wc.y + yv.w * wd.y + b4.y);
      float o2 = gelu_exact(yv.x * wa.z + yv.y * wb.z + yv.z * wc.z + yv.w * wd.z + b4.z);
      float o3 = gelu_exact(yv.x * wa.w + yv.y * wb.w + yv.z * wc.w + yv.w * wd.w + b4.w);
      Half4 p;
      p.a = __floats2half2_rn(o0, o1);
      p.b = __floats2half2_rn(o2, o3);
      *(Half4*)&Gt[r][c0] = p;
    }
  }
  __syncthreads();
  int wv = t >> 6, lane = t & 63;
  int m = lane & 15, quad = lane >> 4;
  {
    int c0 = wv * 16;
    const __half* pa = WtP + (size_t)(c0 + m) * 1024 + quad * 8;
    f32x4 acc0 = {0.f, 0.f, 0.f, 0.f}, acc1 = {0.f, 0.f, 0.f, 0.f};
#pragma unroll 8
    for (int k = 0; k < 1024; k += 32) {
      f16x8 a = *(const f16x8*)(pa + k);
      f16x8 b0 = *(const f16x8*)&Gt[m][quad * 8 + k];
      f16x8 b1 = *(const f16x8*)&Gt[16 + m][quad * 8 + k];
      acc0 = __builtin_amdgcn_mfma_f32_16x16x32_f16(a, b0, acc0, 0, 0, 0);
      acc1 = __builtin_amdgcn_mfma_f32_16x16x32_f16(a, b1, acc1, 0, 0, 0);
    }
    float4 b4 = *(const float4*)&biasP[c0 + quad * 4];
    int row0 = r0 + m, row1 = r0 + 16 + m;
    if constexpr (__is_same(OutT, __half)) {
      Half4 p;
      if (row0 < N) {
        p.a = __floats2half2_rn(acc0[0] + b4.x, acc0[1] + b4.y);
        p.b = __floats2half2_rn(acc0[2] + b4.z, acc0[3] + b4.w);
        *(Half4*)&out[(size_t)row0 * 128 + c0 + quad * 4] = p;
      }
      if (row1 < N) {
        p.a = __floats2half2_rn(acc1[0] + b4.x, acc1[1] + b4.y);
        p.b = __floats2half2_rn(acc1[2] + b4.z, acc1[3] + b4.w);
        *(Half4*)&out[(size_t)row1 * 128 + c0 + quad * 4] = p;
      }
    } else {
      if (row0 < N)
        *(float4*)&out[(size_t)row0 * 128 + c0 + quad * 4] =
            make_float4(acc0[0] + b4.x, acc0[1] + b4.y, acc0[2] + b4.z, acc0[3] + b4.w);
      if (row1 < N)
        *(float4*)&out[(size_t)row1 * 128 + c0 + quad * 4] =
            make_float4(acc1[0] + b4.x, acc1[1] + b4.y, acc1[2] + b4.z, acc1[3] + b4.w);
    }
  }
}

// ---------------- orchestration ----------------

extern "C" void kernel_launch(void* const* d_in, const int* in_sizes, int n_in,
                              void* d_out, int out_size, void* d_ws, size_t ws_size,
                              hipStream_t stream) {
  const float* x   = (const float*)d_in[0];
  const int*   ei  = (const int*)d_in[1];
  const float* w1  = (const float*)d_in[2];
  const float* as1 = (const float*)d_in[3];
  const float* ad1 = (const float*)d_in[4];
  const float* b1  = (const float*)d_in[5];
  const float* w2  = (const float*)d_in[6];
  const float* as2 = (const float*)d_in[7];
  const float* ad2 = (const float*)d_in[8];
  const float* b2  = (const float*)d_in[9];
  const float* w3  = (const float*)d_in[10];
  const float* as3 = (const float*)d_in[11];
  const float* ad3 = (const float*)d_in[12];
  const float* b3  = (const float*)d_in[13];
  const float* rw1 = (const float*)d_in[14];
  const float* rb1 = (const float*)d_in[15];
  const float* rw2 = (const float*)d_in[16];
  const float* rb2 = (const float*)d_in[17];
  const float* lw  = (const float*)d_in[18];
  const float* lb  = (const float*)d_in[19];

  int N = in_sizes[0] / 4;
  int E = in_sizes[1] / 2;
  int ET = E + N;
  int nRow32 = (N + 31) / 32;
  int NP = nRow32 * 32;          // padded rows (10016)
  (void)ws_size;

  char* wsb = (char*)d_ws;
  size_t off = 0;
  auto alloc = [&](size_t bytes) -> void* {
    void* p = wsb + off;
    off += (bytes + 255) & ~(size_t)255;
    return p;
  };
  __half* P16  = (__half*)alloc((size_t)N * 128 * 2);
  __half* Y16  = (__half*)alloc((size_t)8 * NP * 128 * 2);
  float*  Y1   = (float*)alloc((size_t)8 * NP * 4 * 4);
  __half* wt2  = (__half*)alloc((size_t)1024 * 128 * 2);
  __half* wt3  = (__half*)alloc((size_t)1024 * 128 * 2);
  __half* rwt1 = (__half*)alloc((size_t)128 * 1024 * 2);
  __half* rwt2 = (__half*)alloc((size_t)128 * 1024 * 2);
  __half* lwt  = (__half*)alloc((size_t)128 * 1024 * 2);
  float* ws1 = (float*)alloc(8 * 4 * 4);
  float* wd1 = (float*)alloc(8 * 4 * 4);
  float* ws2 = (float*)alloc(8 * 128 * 4);
  float* wd2 = (float*)alloc(8 * 128 * 4);
  float* ws3 = (float*)alloc(8 * 128 * 4);
  float* wd3 = (float*)alloc(8 * 128 * 4);
  float* ssrc   = (float*)alloc((size_t)N * 8 * 4);
  float* sdst   = (float*)alloc((size_t)N * 8 * 4);
  int* counts  = (int*)alloc((size_t)N * 4);
  int* offsets = (int*)alloc((size_t)(N + 1) * 4);
  int* cursor  = (int*)alloc((size_t)N * 4);
  int* srcs    = (int*)alloc((size_t)ET * 4);

  dim3 blk(THREADS);
  dim3 blk512(512);

  hipMemsetAsync(counts, 0, (size_t)N * 4, stream);
  hist_kernel<<<dim3((ET + THREADS - 1) / THREADS), blk, 0, stream>>>(ei, E, ET, counts);
  wconv_all_kernel<<<dim3(32, 32, 5), blk, 0, stream>>>(w2, w3, rw1, rw2, lw,
                                                        wt2, wt3, rwt1, rwt2, lwt);
  sconv_kernel<<<dim3(8, 3), blk, 0, stream>>>(w1, as1, ad1, w2, as2, ad2, w3, as3, ad3,
                                               ws1, wd1, ws2, wd2, ws3, wd3);
  scan_kernel<<<dim3(1), dim3(1024), 0, stream>>>(counts, offsets, cursor, N);
  scatter_kernel<<<dim3((ET + THREADS - 1) / THREADS), blk, 0, stream>>>(ei, E, ET, cursor, srcs);

  dim3 gNode4(N / 4);
  dim3 gRow32(nRow32);

  // ---- layer 1 ----
  scoresX_kernel<<<dim3((N * 8 + THREADS - 1) / THREADS), blk, 0, stream>>>(
      x, ws1, wd1, ssrc, sdst, N * 8);
  attnagg_x<<<gNode4, blk, 0, stream>>>(x, srcs, offsets, ssrc, sdst, Y1, NP);
  tail1_kernel<__half><<<gRow32, blk512, 0, stream>>>(Y1, w1, b1, rwt1, rb1, P16, N, NP);

  // ---- layer 2 ----
  scoresP_kernel<<<gNode4, blk, 0, stream>>>(P16, ws2, wd2, ssrc, sdst);
  attnagg_p<<<gNode4, blk, 0, stream>>>(P16, srcs, offsets, ssrc, sdst, Y16, NP);
  tail_mfma<__half><<<gRow32, blk512, 0, stream>>>(Y16, wt2, b2, rwt2, rb2, P16, N, NP);

  // ---- layer 3 ----
  scoresP_kernel<<<gNode4, blk, 0, stream>>>(P16, ws3, wd3, ssrc, sdst);
  attnagg_p<<<gNode4, blk, 0, stream>>>(P16, srcs, offsets, ssrc, sdst, Y16, NP);
  tail_mfma<float><<<gRow32, blk512, 0, stream>>>(Y16, wt3, b3, lwt, lb, (float*)d_out, N, NP);
}